// Round 10
// baseline (490.053 us; speedup 1.0000x reference)
//
#include <hip/hip_runtime.h>

typedef _Float16 half8_t __attribute__((ext_vector_type(8)));
typedef _Float16 half4_t __attribute__((ext_vector_type(4)));
typedef float floatx4 __attribute__((ext_vector_type(4)));
typedef float f32x16 __attribute__((ext_vector_type(16)));

// async global->LDS, 16B per lane. lds ptr wave-uniform; HW writes lane L at
// ldsbase + L*16.
__device__ inline void gload16(const void* g, void* l) {
  __builtin_amdgcn_global_load_lds(
      (const __attribute__((address_space(1))) unsigned int*)g,
      (__attribute__((address_space(3))) unsigned int*)l, 16, 0, 0);
}

// == 128x128 BT GEMM, 32x32x16, 512 thr, 64KiB LDS -> 2 blk/CU, 4 w/SIMD ==
// C[m,n] = sum_h A[m,h]*B[n,h] (+bias). K=1024 = 16 tiles of BK=64.
// 512 threads = 8 waves in 2(wr) x 4(wc); per-wave C slice 64x32
// (2 mi-rows of 32 x 1 col of 32) -> acc = 2 x f32x16 = 32 VGPR only.
// WHY: r2..r9 all ran 1 block/CU @ 2 waves/SIMD -> every barrier/drain
// window idles the MFMA pipe (MfmaUtil stuck 26-33% across 3 schedules).
// This config gives 4 waves/SIMD across 2 INDEPENDENT blocks (decoupled
// barriers) -> m97/m114-style TLP overlap fills the stalls.
//
// LDS per operand per parity: 128 rows x 8 kb chunks = 16KB;
//   slot(m,kb) = m*8 + (kb ^ (m&7))   [XOR involution, both sides]
// Staging coalesced (r7): instr (wid,i) covers chunks c0..c0+63,
//   c0 = (wid*2+i)*64 (c0/8 % 8 == 0); lane L -> row c0/8 + L/8,
//   kb = (L&7)^(L/8); 8-lane groups read one aligned 128B row segment.
//   laneoff = (L>>3)*ld + ((L&7)^(L>>3))*8.
// Frag reads: byte = row*128 + xk*16, xk[ks] = (ks*2+hi) ^ (lane&7).
//
// Per K-tile t (p=t&1, q=p^1): [stage A,B of t+1 -> q (4 gload16/wave)]
// [read 12 frags from p] [lgkm(0)] [8 MFMA, ks-outer: 2 indep chains]
// [vmcnt(0)] [barrier]. Stages hit q while reads hit p -> race-free
// (r8-proven skeleton). vmcnt(0) residual hidden by the co-resident block.
constexpr int NT = 16;  // K / 64

// A frags: mi 0..1 -> row wr*64 + mi*32 + lo
__device__ inline void lda_frags(const char* sA, int wr, int lo, const int* xk,
                                 half8_t af[2][4]) {
#pragma unroll
  for (int mi = 0; mi < 2; ++mi) {
    const int row = wr * 64 + mi * 32 + lo;
#pragma unroll
    for (int ks = 0; ks < 4; ++ks)
      af[mi][ks] = *(const half8_t*)(sA + (size_t)(row * 128 + xk[ks] * 16));
  }
}

// B frags: row wc*32 + lo
__device__ inline void ldb_frags(const char* sB, int wc, int lo, const int* xk,
                                 half8_t bf[4]) {
  const int row = wc * 32 + lo;
#pragma unroll
  for (int ks = 0; ks < 4; ++ks)
    bf[ks] = *(const half8_t*)(sB + (size_t)(row * 128 + xk[ks] * 16));
}

// stage one 128x64 operand K-tile u into parity-resolved base (2 gload16).
__device__ inline void stage_op(const _Float16* __restrict__ X, long laneoff,
                                int ldx, int u, char* opbase, int wid) {
#pragma unroll
  for (int i = 0; i < 2; ++i) {
    const int c0 = (wid * 2 + i) * 64;
    gload16(X + (long)(c0 >> 3) * ldx + u * 64 + laneoff,
            opbase + (size_t)c0 * 16);
  }
}

template <typename OT, int BIAS, int GX, int GY>
__global__ __launch_bounds__(512, 4) void gemm128(
    const _Float16* __restrict__ A, long As, int lda,
    const _Float16* __restrict__ B, long Bs, int ldb,
    OT* __restrict__ C, long Cs, int ldc, const float* __restrict__ bias,
    int biasStride) {
  __shared__ char smem[65536];  // A: p*16384, B: 32768 + p*16384

  // XCD chunk swizzle (grids 1024/2048, always %8==0)
  const int id = blockIdx.x;
  const int chunk = gridDim.x >> 3;
  const int nid = (id & 7) * chunk + (id >> 3);
  const int bx = nid % GX;
  const int by = (nid / GX) % GY;
  const int bz = nid / (GX * GY);

  const int tid = threadIdx.x;
  const int lane = tid & 63;
  const int wid = tid >> 6;   // 0..7
  const int wr = wid >> 2;    // 0..1
  const int wc = wid & 3;     // 0..3
  const int lo = lane & 31;
  const int hi = lane >> 5;
  const int l7 = lane & 7;
  const int l8 = lane >> 3;
  const long laneA = (long)l8 * lda + ((l7 ^ l8) << 3);
  const long laneB = (long)l8 * ldb + ((l7 ^ l8) << 3);
  int xk[4];
#pragma unroll
  for (int ks = 0; ks < 4; ++ks) xk[ks] = (ks * 2 + hi) ^ l7;

  const long m0 = (long)by * 128;
  const long n0 = (long)bx * 128;
  const _Float16* Ab = A + (long)bz * As + m0 * (long)lda;
  const _Float16* Bb = B + (long)bz * Bs + n0 * (long)ldb;
  C += (long)bz * Cs;

  f32x16 acc[2] = {};
  half8_t af[2][4], bf[4];

  // ---- prologue: tile 0 -> parity 0
  stage_op(Ab, laneA, lda, 0, smem, wid);
  stage_op(Bb, laneB, ldb, 0, smem + 32768, wid);
  asm volatile("s_waitcnt vmcnt(0)" ::: "memory");
  __builtin_amdgcn_s_barrier();

  for (int t = 0; t < NT; ++t) {
    const int p = t & 1, q = p ^ 1;
    char* sAp = smem + p * 16384;
    char* sBp = smem + 32768 + p * 16384;
    char* sAq = smem + q * 16384;
    char* sBq = smem + 32768 + q * 16384;
    const int u1 = (t + 1 < NT) ? t + 1 : NT - 1;  // tail dup -> dead parity

    // stage t+1 -> q (disjoint from this tile's reads on p)
    stage_op(Ab, laneA, lda, u1, sAq, wid);
    stage_op(Bb, laneB, ldb, u1, sBq, wid);

    // frags from p
    lda_frags(sAp, wr, lo, xk, af);
    ldb_frags(sBp, wc, lo, xk, bf);
    asm volatile("s_waitcnt lgkmcnt(0)" ::: "memory");

    __builtin_amdgcn_s_setprio(1);
#pragma unroll
    for (int ks = 0; ks < 4; ++ks)
#pragma unroll
      for (int mi = 0; mi < 2; ++mi)
        acc[mi] = __builtin_amdgcn_mfma_f32_32x32x16_f16(af[mi][ks], bf[ks],
                                                         acc[mi], 0, 0, 0);
    __builtin_amdgcn_s_setprio(0);

    // own stages drained, barrier syncs all waves -> q complete for t+1
    asm volatile("s_waitcnt vmcnt(0)" ::: "memory");
    __builtin_amdgcn_s_barrier();
  }

  // epilogue: 32x32 C/D layout col = lo, row = (e&3) + 8*(e>>2) + 4*hi
#pragma unroll
  for (int mi = 0; mi < 2; ++mi) {
    const int r0 = wr * 64 + mi * 32 + 4 * hi;
    const int cc = (int)n0 + wc * 32 + lo;
#pragma unroll
    for (int e = 0; e < 16; ++e) {
      const long row = m0 + r0 + (e & 3) + 8 * (e >> 2);
      float v = acc[mi][e];
      if constexpr (BIAS == 1) v += bias[bz * biasStride + cc];
      if constexpr (BIAS == 2) v += bias[(int)row];
      C[row * (long)ldc + cc] = (OT)v;
    }
  }
}

// ===================== auxiliary kernels =====================

// fp32 -> fp16, one float4 chunk per thread, 3 tensors of 16M floats each.
__global__ __launch_bounds__(256) void convert_x(const float* __restrict__ x0,
                                                 const float* __restrict__ x1,
                                                 const float* __restrict__ x2,
                                                 _Float16* __restrict__ out) {
  int i = blockIdx.x * 256 + threadIdx.x;  // 12582912 chunks total
  int t = i >> 22;                         // 4194304 chunks per tensor
  int j = i & 4194303;
  const float* src = (t == 0) ? x0 : (t == 1) ? x1 : x2;
  floatx4 v = ((const floatx4*)src)[j];
  half4_t h = {(_Float16)v[0], (_Float16)v[1], (_Float16)v[2], (_Float16)v[3]};
  ((half4_t*)out)[i] = h;
}

__global__ __launch_bounds__(256) void convert_w(const float* __restrict__ Wq,
                                                 const float* __restrict__ Wk,
                                                 const float* __restrict__ Wv,
                                                 _Float16* __restrict__ out) {
  int i = blockIdx.x * 256 + threadIdx.x;  // 786432 chunks total
  int t = i >> 18;                         // 262144 chunks per tensor
  int j = i & 262143;
  const float* src = (t == 0) ? Wq : (t == 1) ? Wk : Wv;
  floatx4 v = ((const floatx4*)src)[j];
  half4_t h = {(_Float16)v[0], (_Float16)v[1], (_Float16)v[2], (_Float16)v[3]};
  ((half4_t*)out)[i] = h;
}

__global__ __launch_bounds__(256) void pack_bias(const float* __restrict__ bq,
                                                 const float* __restrict__ bk,
                                                 const float* __restrict__ bv,
                                                 float* __restrict__ out) {
  int b = blockIdx.x;
  const float* src = (b == 0) ? bq : (b == 1) ? bk : bv;
  ((floatx4*)out)[b * 256 + threadIdx.x] =
      ((const floatx4*)src)[threadIdx.x];
}

// Row softmax over 1024 fp16 scores, fp32 math, fp16 result in place.
__global__ __launch_bounds__(256) void softmax_rows_h(_Float16* __restrict__ S) {
  long row = blockIdx.x;
  _Float16* Sr = S + row * 1024;
  int tid = threadIdx.x, lane = tid & 63, wid = tid >> 6;
  half4_t x = ((const half4_t*)Sr)[tid];
  float x0 = x[0], x1 = x[1], x2 = x[2], x3 = x[3];
  float mx = fmaxf(fmaxf(x0, x1), fmaxf(x2, x3));
#pragma unroll
  for (int off = 32; off > 0; off >>= 1) mx = fmaxf(mx, __shfl_xor(mx, off));
  __shared__ float redm[4];
  if (lane == 0) redm[wid] = mx;
  __syncthreads();
  mx = fmaxf(fmaxf(redm[0], redm[1]), fmaxf(redm[2], redm[3]));
  float e0 = __expf(x0 - mx), e1 = __expf(x1 - mx);
  float e2 = __expf(x2 - mx), e3 = __expf(x3 - mx);
  float s = e0 + e1 + e2 + e3;
#pragma unroll
  for (int off = 32; off > 0; off >>= 1) s += __shfl_xor(s, off);
  __shared__ float reds[4];
  if (lane == 0) reds[wid] = s;
  __syncthreads();
  s = reds[0] + reds[1] + reds[2] + reds[3];
  float inv = 1.0f / s;
  half4_t h = {(_Float16)(e0 * inv), (_Float16)(e1 * inv),
               (_Float16)(e2 * inv), (_Float16)(e3 * inv)};
  ((half4_t*)Sr)[tid] = h;
}

extern "C" void kernel_launch(void* const* d_in, const int* in_sizes, int n_in,
                              void* d_out, int out_size, void* d_ws,
                              size_t ws_size, hipStream_t stream) {
  (void)in_sizes; (void)n_in; (void)out_size; (void)ws_size;
  const float* meme  = (const float*)d_in[0];
  const float* text  = (const float*)d_in[1];
  const float* emoji = (const float*)d_in[2];
  const float* Wq = (const float*)d_in[3];
  const float* bq = (const float*)d_in[4];
  const float* Wk = (const float*)d_in[5];
  const float* bk = (const float*)d_in[6];
  const float* Wv = (const float*)d_in[7];
  const float* bv = (const float*)d_in[8];

  const long MB = 1024 * 1024;
  char* ws = (char*)d_ws;
  // [0,6) MB:    hWq/hWk/hWv fp16 (contiguous, stride 1M halves)
  // [6,7):       packed bias 3*1024 fp32
  // [7,39) MB:   meme_h  -> dead after QK GEMM -> reused as S (fp16, 32MB)
  // [39,71) MB:  text_h  -> dead after QK GEMM -> reused as Vt (fp16, 32MB)
  // [71,103) MB: emoji_h -> dead after Vt GEMM
  // [103,135):   Qh fp16   [135,167): Kh fp16
  _Float16* hWq = (_Float16*)ws;
  float* pbias  = (float*)(ws + 6 * MB);
  _Float16* mh  = (_Float16*)(ws + 7 * MB);
  _Float16* th  = (_Float16*)(ws + 39 * MB);
  _Float16* eh  = (_Float16*)(ws + 71 * MB);
  _Float16* Qh  = (_Float16*)(ws + 103 * MB);
  _Float16* Kh  = (_Float16*)(ws + 135 * MB);
  _Float16* S   = mh;  // aliases meme_h (dead by then)
  _Float16* Vt  = th;  // aliases text_h (dead by then)
  _Float16* hWv = hWq + 2 * MB;

  dim3 blk(256), blk5(512);
  convert_w<<<3072, blk, 0, stream>>>(Wq, Wk, Wv, hWq);
  pack_bias<<<3, blk, 0, stream>>>(bq, bk, bv, pbias);
  convert_x<<<49152, blk, 0, stream>>>(meme, text, emoji, mh);

  // Q,K projections batched (z=2, contiguous workspace): M=16384, N=1024.
  gemm128<_Float16, 1, 8, 128><<<dim3(2048), blk5, 0, stream>>>(
      mh, 16777216, 1024, hWq, 1048576, 1024, Qh, 16777216, 1024, pbias, 1024);
  // Vt[a, b*L+l] = sum_h Wv[a,h]*emoji[b,l,h] + bv[a]  (V transposed)
  gemm128<_Float16, 2, 128, 8><<<dim3(1024), blk5, 0, stream>>>(
      hWv, 0, 1024, eh, 0, 1024, Vt, 0, 16384, pbias + 2048, 0);
  // S[b] = Q[b] @ K[b]^T -> fp16. per-batch 1024x1024, z=16.
  gemm128<_Float16, 0, 8, 8><<<dim3(1024), blk5, 0, stream>>>(
      Qh, 1048576, 1024, Kh, 1048576, 1024, S, 1048576, 1024, nullptr, 0);
  // softmax rows, fp16 in place
  softmax_rows_h<<<16384, blk, 0, stream>>>(S);
  // O[b] = P[b] @ V[b] via Vt: C[q,a] = sum_k P[q,k] * Vt[a, b*1024+k]
  gemm128<float, 0, 8, 8><<<dim3(1024), blk5, 0, stream>>>(
      S, 1048576, 1024, Vt, 1024, 16384, (float*)d_out, 1048576, 1024,
      nullptr, 0);
}

// Round 12
// 441.392 us; speedup vs baseline: 1.1102x; 1.1102x over previous
//
#include <hip/hip_runtime.h>

typedef _Float16 half8_t __attribute__((ext_vector_type(8)));
typedef _Float16 half4_t __attribute__((ext_vector_type(4)));
typedef float floatx4 __attribute__((ext_vector_type(4)));

// async global->LDS, 16B per lane. lds ptr wave-uniform; HW writes lane L at
// ldsbase + L*16.
__device__ inline void gload16(const void* g, void* l) {
  __builtin_amdgcn_global_load_lds(
      (const __attribute__((address_space(1))) unsigned int*)g,
      (__attribute__((address_space(3))) unsigned int*)l, 16, 0, 0);
}

// ======== 256x256 BT GEMM — m201 8-phase template port (fp16) =========
// C[m,n] = sum_h A[m,h]*B[n,h] (+bias). K=1024 = 16 tiles of BK=64.
// 512 thr = 8 waves, 2(wm) x 4(wn); per-wave output 128x64
// -> acc[8 mf][4 nf] f32x4 = 128 VGPR. MFMA 16x16x32_f16 (r2-verified
// mapping: A lane l: A[m=l&15][k = kk*32 + (l>>4)*8 + j];
// C/D col=l&15, row=(l>>4)*4+r).
// LDS 128 KiB = [parity][operand][half] x 16KB. Half = [128 rows][64 k] fp16,
// row-major 128B rows, 2-BIT swizzle: c ^= ((row&6)<<3)  [strengthened
// st_16x32: spreads the 8 rows of each 8-lane ds_read group across FOUR 16B
// columns -> 2 lanes/bank = free (m136), vs 4-way with the 1-bit form].
// Staging: gload_lds linear dest + PRE-SWIZZLED global src (both-sides rule):
// each 8-lane group stages one full 128B row with chunks permuted in-row ->
// still one aligned 128B segment per group (coalesced).
//   laneoff = (L>>3)*ld + ((L&7)*8 ^ (((L>>3)&6)<<2))   [elements]
//
// Phase schedule per K-tile t (p=t&1, q=p^1), 8 phases / 2 tiles:
//  Ph1: read A@kk0 (8) + B nf01@kk0 (2); stage t+1.A1 -> q.A1
//  Ph2: read B nf23@kk0 (2);             stage t+1.B0 -> q.B0
//  Ph3: read A@kk1 (8) + B nf23@kk1 (2); stage t+1.B1 -> q.B1
//  Ph4: read B nf01@kk1 (2);             stage t+2.A0 -> p.A0; vmcnt(2)
// each phase: [reads; stage; (vmcnt); barrier; lgkm(0); setprio1; 16 MFMA;
// setprio0; barrier]. Slot-death: q.{A1,B0,B1} dead since t-1.Ph1/3/4 reads
// (lgkm-drained + barriered); p.A0 dead after t.Ph3. vmcnt(2) at Ph4 drains
// everything tile t+1 reads, keeps Ph4's own 2 — never 0 in-loop.
// Prologue: 5 halves, vmcnt(2). Tail: clamped re-stages hit dead-parity
// slots behind the same barriers (race-free) or rewrite identical bytes.
constexpr int NT = 16;  // K / 64

__device__ inline int swz(int row, int colbyte) {
  return row * 128 + (colbyte ^ ((row & 6) << 3));
}

// 8 A-frags (one kk) from the wave's own 16KB A-half region.
__device__ inline void lda8(const char* sAh, int kk, int l15, int l4,
                            half8_t af[8]) {
#pragma unroll
  for (int mf = 0; mf < 8; ++mf)
    af[mf] = *(const half8_t*)(sAh + swz(mf * 16 + l15, kk * 64 + l4 * 16));
}

// 2 B-frags (one nf-pair, one kk) from the wave's B-half region.
__device__ inline void ldb2(const char* sBh, int rbase, int kk, int l15,
                            int l4, half8_t bf[2]) {
#pragma unroll
  for (int nf = 0; nf < 2; ++nf)
    bf[nf] = *(const half8_t*)(
        sBh + swz(rbase + nf * 16 + l15, kk * 64 + l4 * 16));
}

template <int NP>
__device__ inline void mfma16(const half8_t af[8], const half8_t bf[2],
                              floatx4 acc[8][4]) {
  __builtin_amdgcn_s_setprio(1);
#pragma unroll
  for (int mf = 0; mf < 8; ++mf)
#pragma unroll
    for (int j = 0; j < 2; ++j)
      acc[mf][NP * 2 + j] = __builtin_amdgcn_mfma_f32_16x16x32_f16(
          af[mf], bf[j], acc[mf][NP * 2 + j], 0, 0, 0);
  __builtin_amdgcn_s_setprio(0);
}

// stage one 16KB half of K-tile u into region. Xh already includes block
// tile offset + half offset. 2 gload16/wave; wave wid covers rows
// wid*16+i*8 .. +8. laneoff pre-applies the row-swizzle permutation.
__device__ inline void stage_half(const _Float16* __restrict__ Xh,
                                  long laneoff, int ldx, int u, char* region,
                                  int wid) {
#pragma unroll
  for (int i = 0; i < 2; ++i)
    gload16(Xh + (long)(wid * 16 + i * 8) * ldx + u * 64 + laneoff,
            region + (size_t)(wid * 2 + i) * 1024);
}

template <typename OT, int BIAS, int GX, int GY>
__global__ __launch_bounds__(512, 2) void gemm256(
    const _Float16* __restrict__ A, long As, int lda,
    const _Float16* __restrict__ B, long Bs, int ldb,
    OT* __restrict__ C, long Cs, int ldc, const float* __restrict__ bias,
    int biasStride) {
  __shared__ char smem[131072];
  // A: parity*32768 + half*16384 ; B: 65536 + parity*32768 + half*16384

  // XCD chunk swizzle (grids 256/512, always %8==0)
  const int id = blockIdx.x;
  const int chunk = gridDim.x >> 3;
  const int nid = (id & 7) * chunk + (id >> 3);
  const int bx = nid % GX;
  const int by = (nid / GX) % GY;
  const int bz = nid / (GX * GY);

  const int tid = threadIdx.x;
  const int lane = tid & 63;
  const int wid = tid >> 6;
  const int wm = wid >> 2;       // 0..1 : rows wm*128..+128
  const int wn = wid & 3;        // 0..3 : cols wn*64..+64
  const int l15 = lane & 15;
  const int l4 = lane >> 4;      // 0..3
  const int brow = (wn & 1) * 64;  // wave's row base inside its B-half
  const int lperm = ((lane & 7) * 8) ^ (((lane >> 3) & 6) << 2);  // elements
  const long laneA = (long)(lane >> 3) * lda + lperm;
  const long laneB = (long)(lane >> 3) * ldb + lperm;

  const long m0 = (long)by * 256;
  const long n0 = (long)bx * 256;
  const _Float16* Ab = A + (long)bz * As + m0 * (long)lda;
  const _Float16* Bb = B + (long)bz * Bs + n0 * (long)ldb;
  const _Float16* Ah0 = Ab;                        // A rows [0,128)
  const _Float16* Ah1 = Ab + 128 * (long)lda;      // A rows [128,256)
  const _Float16* Bh0 = Bb;
  const _Float16* Bh1 = Bb + 128 * (long)ldb;
  C += (long)bz * Cs;

  floatx4 acc[8][4] = {};
  half8_t af[8], bf01[2], bf23[2];

  // ---- prologue: t0.{A0,A1,B0,B1} -> par0; t1.A0 -> par1; vmcnt(2)
  {
    char* p0 = smem;
    char* p0b = smem + 65536;
    stage_half(Ah0, laneA, lda, 0, p0, wid);
    stage_half(Ah1, laneA, lda, 0, p0 + 16384, wid);
    stage_half(Bh0, laneB, ldb, 0, p0b, wid);
    stage_half(Bh1, laneB, ldb, 0, p0b + 16384, wid);
    stage_half(Ah0, laneA, lda, 1, smem + 32768, wid);  // t1.A0 -> par1.A0
    asm volatile("s_waitcnt vmcnt(2)" ::: "memory");
    __builtin_amdgcn_s_barrier();
  }

  for (int t = 0; t < NT; ++t) {
    const int p = t & 1, q = p ^ 1;
    char* pAbase = smem + p * 32768;
    char* pBbase = smem + 65536 + p * 32768;
    char* qAbase = smem + q * 32768;
    char* qBbase = smem + 65536 + q * 32768;
    const char* myA = pAbase + wm * 16384;           // wave's A-half
    const char* myB = pBbase + (wn >> 1) * 16384;    // wave's B-half
    const int u1 = (t + 1 < NT) ? t + 1 : NT - 1;
    const int u2 = (t + 2 < NT) ? t + 2 : NT - 1;

    // ---- Ph1: A@kk0 + B nf01@kk0 ; stage t+1.A1 -> q.A1
    lda8(myA, 0, l15, l4, af);
    ldb2(myB, brow + 0, 0, l15, l4, bf01);
    stage_half(Ah1, laneA, lda, u1, qAbase + 16384, wid);
    __builtin_amdgcn_s_barrier();
    asm volatile("s_waitcnt lgkmcnt(0)" ::: "memory");
    mfma16<0>(af, bf01, acc);
    __builtin_amdgcn_s_barrier();

    // ---- Ph2: B nf23@kk0 ; stage t+1.B0 -> q.B0
    ldb2(myB, brow + 32, 0, l15, l4, bf23);
    stage_half(Bh0, laneB, ldb, u1, qBbase, wid);
    __builtin_amdgcn_s_barrier();
    asm volatile("s_waitcnt lgkmcnt(0)" ::: "memory");
    mfma16<1>(af, bf23, acc);
    __builtin_amdgcn_s_barrier();

    // ---- Ph3: A@kk1 + B nf23@kk1 ; stage t+1.B1 -> q.B1
    lda8(myA, 1, l15, l4, af);
    ldb2(myB, brow + 32, 1, l15, l4, bf23);
    stage_half(Bh1, laneB, ldb, u1, qBbase + 16384, wid);
    __builtin_amdgcn_s_barrier();
    asm volatile("s_waitcnt lgkmcnt(0)" ::: "memory");
    mfma16<1>(af, bf23, acc);
    __builtin_amdgcn_s_barrier();

    // ---- Ph4: B nf01@kk1 ; stage t+2.A0 -> p.A0 (dead after Ph3)
    ldb2(myB, brow + 0, 1, l15, l4, bf01);
    stage_half(Ah0, laneA, lda, u2, pAbase, wid);
    asm volatile("s_waitcnt vmcnt(2)" ::: "memory");  // t+1 fully resident
    __builtin_amdgcn_s_barrier();
    asm volatile("s_waitcnt lgkmcnt(0)" ::: "memory");
    mfma16<0>(af, bf01, acc);
    __builtin_amdgcn_s_barrier();
  }

  asm volatile("s_waitcnt vmcnt(0)" ::: "memory");

  // epilogue: 16x16 C/D layout col = l15, row = l4*4 + r
#pragma unroll
  for (int mf = 0; mf < 8; ++mf) {
    const int r0 = wm * 128 + mf * 16 + l4 * 4;
#pragma unroll
    for (int nf = 0; nf < 4; ++nf) {
      const int cc = (int)n0 + wn * 64 + nf * 16 + l15;
#pragma unroll
      for (int r = 0; r < 4; ++r) {
        const long row = m0 + r0 + r;
        float v = acc[mf][nf][r];
        if constexpr (BIAS == 1) v += bias[bz * biasStride + cc];
        if constexpr (BIAS == 2) v += bias[(int)row];
        C[row * (long)ldc + cc] = (OT)v;
      }
    }
  }
}

// ===================== auxiliary kernels =====================

// fp32 -> fp16, one float4 chunk per thread, 3 tensors of 16M floats each.
__global__ __launch_bounds__(256) void convert_x(const float* __restrict__ x0,
                                                 const float* __restrict__ x1,
                                                 const float* __restrict__ x2,
                                                 _Float16* __restrict__ out) {
  int i = blockIdx.x * 256 + threadIdx.x;  // 12582912 chunks total
  int t = i >> 22;                         // 4194304 chunks per tensor
  int j = i & 4194303;
  const float* src = (t == 0) ? x0 : (t == 1) ? x1 : x2;
  floatx4 v = ((const floatx4*)src)[j];
  half4_t h = {(_Float16)v[0], (_Float16)v[1], (_Float16)v[2], (_Float16)v[3]};
  ((half4_t*)out)[i] = h;
}

__global__ __launch_bounds__(256) void convert_w(const float* __restrict__ Wq,
                                                 const float* __restrict__ Wk,
                                                 const float* __restrict__ Wv,
                                                 _Float16* __restrict__ out) {
  int i = blockIdx.x * 256 + threadIdx.x;  // 786432 chunks total
  int t = i >> 18;                         // 262144 chunks per tensor
  int j = i & 262143;
  const float* src = (t == 0) ? Wq : (t == 1) ? Wk : Wv;
  floatx4 v = ((const floatx4*)src)[j];
  half4_t h = {(_Float16)v[0], (_Float16)v[1], (_Float16)v[2], (_Float16)v[3]};
  ((half4_t*)out)[i] = h;
}

__global__ __launch_bounds__(256) void pack_bias(const float* __restrict__ bq,
                                                 const float* __restrict__ bk,
                                                 const float* __restrict__ bv,
                                                 float* __restrict__ out) {
  int b = blockIdx.x;
  const float* src = (b == 0) ? bq : (b == 1) ? bk : bv;
  ((floatx4*)out)[b * 256 + threadIdx.x] =
      ((const floatx4*)src)[threadIdx.x];
}

// Row softmax over 1024 fp16 scores, fp32 math, fp16 result in place.
__global__ __launch_bounds__(256) void softmax_rows_h(_Float16* __restrict__ S) {
  long row = blockIdx.x;
  _Float16* Sr = S + row * 1024;
  int tid = threadIdx.x, lane = tid & 63, wid = tid >> 6;
  half4_t x = ((const half4_t*)Sr)[tid];
  float x0 = x[0], x1 = x[1], x2 = x[2], x3 = x[3];
  float mx = fmaxf(fmaxf(x0, x1), fmaxf(x2, x3));
#pragma unroll
  for (int off = 32; off > 0; off >>= 1) mx = fmaxf(mx, __shfl_xor(mx, off));
  __shared__ float redm[4];
  if (lane == 0) redm[wid] = mx;
  __syncthreads();
  mx = fmaxf(fmaxf(redm[0], redm[1]), fmaxf(redm[2], redm[3]));
  float e0 = __expf(x0 - mx), e1 = __expf(x1 - mx);
  float e2 = __expf(x2 - mx), e3 = __expf(x3 - mx);
  float s = e0 + e1 + e2 + e3;
#pragma unroll
  for (int off = 32; off > 0; off >>= 1) s += __shfl_xor(s, off);
  __shared__ float reds[4];
  if (lane == 0) reds[wid] = s;
  __syncthreads();
  s = reds[0] + reds[1] + reds[2] + reds[3];
  float inv = 1.0f / s;
  half4_t h = {(_Float16)(e0 * inv), (_Float16)(e1 * inv),
               (_Float16)(e2 * inv), (_Float16)(e3 * inv)};
  ((half4_t*)Sr)[tid] = h;
}

extern "C" void kernel_launch(void* const* d_in, const int* in_sizes, int n_in,
                              void* d_out, int out_size, void* d_ws,
                              size_t ws_size, hipStream_t stream) {
  (void)in_sizes; (void)n_in; (void)out_size; (void)ws_size;
  const float* meme  = (const float*)d_in[0];
  const float* text  = (const float*)d_in[1];
  const float* emoji = (const float*)d_in[2];
  const float* Wq = (const float*)d_in[3];
  const float* bq = (const float*)d_in[4];
  const float* Wk = (const float*)d_in[5];
  const float* bk = (const float*)d_in[6];
  const float* Wv = (const float*)d_in[7];
  const float* bv = (const float*)d_in[8];

  const long MB = 1024 * 1024;
  char* ws = (char*)d_ws;
  // [0,6) MB:    hWq/hWk/hWv fp16 (contiguous, stride 1M halves)
  // [6,7):       packed bias 3*1024 fp32
  // [7,39) MB:   meme_h  -> dead after QK GEMM -> reused as S (fp16, 32MB)
  // [39,71) MB:  text_h  -> dead after QK GEMM -> reused as Vt (fp16, 32MB)
  // [71,103) MB: emoji_h -> dead after Vt GEMM
  // [103,135):   Qh fp16   [135,167): Kh fp16
  _Float16* hWq = (_Float16*)ws;
  float* pbias  = (float*)(ws + 6 * MB);
  _Float16* mh  = (_Float16*)(ws + 7 * MB);
  _Float16* th  = (_Float16*)(ws + 39 * MB);
  _Float16* eh  = (_Float16*)(ws + 71 * MB);
  _Float16* Qh  = (_Float16*)(ws + 103 * MB);
  _Float16* Kh  = (_Float16*)(ws + 135 * MB);
  _Float16* S   = mh;  // aliases meme_h (dead by then)
  _Float16* Vt  = th;  // aliases text_h (dead by then)
  _Float16* hWv = hWq + 2 * MB;

  dim3 blk(256), blk5(512);
  convert_w<<<3072, blk, 0, stream>>>(Wq, Wk, Wv, hWq);
  pack_bias<<<3, blk, 0, stream>>>(bq, bk, bv, pbias);
  convert_x<<<49152, blk, 0, stream>>>(meme, text, emoji, mh);

  // Q,K projections batched (z=2, contiguous workspace): M=16384, N=1024.
  gemm256<_Float16, 1, 4, 64><<<dim3(512), blk5, 0, stream>>>(
      mh, 16777216, 1024, hWq, 1048576, 1024, Qh, 16777216, 1024, pbias, 1024);
  // Vt[a, b*L+l] = sum_h Wv[a,h]*emoji[b,l,h] + bv[a]  (V transposed)
  gemm256<_Float16, 2, 64, 4><<<dim3(256), blk5, 0, stream>>>(
      hWv, 0, 1024, eh, 0, 1024, Vt, 0, 16384, pbias + 2048, 0);
  // S[b] = Q[b] @ K[b]^T -> fp16. per-batch 1024x1024, z=16.
  gemm256<_Float16, 0, 4, 4><<<dim3(256), blk5, 0, stream>>>(
      Qh, 1048576, 1024, Kh, 1048576, 1024, S, 1048576, 1024, nullptr, 0);
  // softmax rows, fp16 in place
  softmax_rows_h<<<16384, blk, 0, stream>>>(S);
  // O[b] = P[b] @ V[b] via Vt: C[q,a] = sum_k P[q,k] * Vt[a, b*1024+k]
  gemm256<float, 0, 4, 4><<<dim3(256), blk5, 0, stream>>>(
      S, 1048576, 1024, Vt, 1024, 16384, (float*)d_out, 1048576, 1024,
      nullptr, 0);
}